// Round 17
// baseline (420.397 us; speedup 1.0000x reference)
//
#include <hip/hip_runtime.h>
#include <hip/hip_bf16.h>

#define B_ 16
#define T_ 12
#define N_ 2000
#define E_ 8000
#define M_ 32000                 // B_*N_
#define ETOT (B_*E_ + M_)        // 160000 edges incl. self loops
#define D_ 64

typedef __hip_bfloat16 bf16;
typedef unsigned short u16;
typedef __attribute__((ext_vector_type(8))) _Float16 half8;
typedef __attribute__((ext_vector_type(2))) _Float16 h2v;
typedef __attribute__((ext_vector_type(4))) float f32x4;

__device__ __forceinline__ float bfu(u16 u){ return __uint_as_float(((unsigned int)u)<<16); }
__device__ __forceinline__ u16 f2bu(float f){
  unsigned int x = __float_as_uint(f);
  x += 0x7FFFu + ((x >> 16) & 1u);
  return (u16)(x >> 16);
}
__device__ __forceinline__ u16 f2h(float f){
  _Float16 h = (_Float16)f; u16 r; __builtin_memcpy(&r, &h, 2); return r;
}
__device__ __forceinline__ float h2f(u16 u){
  _Float16 h; __builtin_memcpy(&h, &u, 2); return (float)h;
}
__device__ __forceinline__ h2v u2h(unsigned u){ h2v r; __builtin_memcpy(&r,&u,4); return r; }
__device__ __forceinline__ unsigned pk2(float a, float b){
  return (unsigned)f2h(a) | ((unsigned)f2h(b)<<16);
}

// ---------------- weight prep: f16 MFMA B-fragments + PE table ----------------
__global__ void k_prep(const float* __restrict__ Wqkv, const float* __restrict__ Wo,
                       const float* __restrict__ Wf1, const float* __restrict__ Wf2,
                       u16* __restrict__ wqB, u16* __restrict__ woB,
                       u16* __restrict__ w1B, u16* __restrict__ w2B,
                       float* __restrict__ peT){
  int i = blockIdx.x*256 + threadIdx.x;    // 260 blocks
  if(i < 24576){
    int l=i/12288, r=i-l*12288;
    int nt=r>>10, r2=r&1023, c=r2>>9, r3=r2&511, lane=r3>>3, jj=r3&7;
    int m=lane&15, q=lane>>4;
    wqB[i] = f2h(Wqkv[l*12288 + (nt*16+m)*64 + c*32 + q*8 + jj]);
  } else if(i < 32768){
    int k2=i-24576;
    int l=k2>>12, r=k2&4095;
    int nt=r>>10, r2=r&1023, c=r2>>9, r3=r2&511, lane=r3>>3, jj=r3&7;
    int m=lane&15, q=lane>>4;
    woB[k2] = f2h(Wo[l*4096 + (nt*16+m)*64 + c*32 + q*8 + jj]);
  } else if(i < 49152){
    int k2=i-32768;
    int l=k2>>13, r=k2&8191;
    int nt=r>>10, r2=r&1023, c=r2>>9, r3=r2&511, lane=r3>>3, jj=r3&7;
    int m=lane&15, q=lane>>4;
    w1B[k2] = f2h(Wf1[l*8192 + (nt*16+m)*64 + c*32 + q*8 + jj]);
  } else if(i < 65536){
    int k2=i-49152;
    int l=k2>>13, r=k2&8191;
    int nt=r>>11, r2=r&2047, c=r2>>9, r3=r2&511, lane=r3>>3, jj=r3&7;
    int m=lane&15, q=lane>>4;
    w2B[k2] = f2h(Wf2[l*8192 + (nt*16+m)*128 + c*32 + q*8 + jj]);
  } else {
    int i2 = i - 65536;
    if(i2 < 768){
      int t=i2>>6, ch=i2&63;
      float ang = (float)t * __expf(-0.14391156463f * (float)(ch & ~1));
      peT[i2] = (ch&1) ? __cosf(ang) : __sinf(ang);
    }
  }
}

// ---------------- CSR build ----------------
__global__ void k_hist(const int* __restrict__ ei, int* __restrict__ deg){
  int e = blockIdx.x*256 + threadIdx.x; if(e>=ETOT) return;
  int dst;
  if (e < B_*E_){ int b = e / E_; int k = e - b*E_; dst = ei[E_ + k] + b*N_; }
  else dst = e - B_*E_;
  atomicAdd(&deg[dst], 1);
}

__global__ void k_scan1(const int* __restrict__ deg, int* __restrict__ offs, int* __restrict__ bsums){
  __shared__ int s[256];
  int tid = threadIdx.x; int g = blockIdx.x*256 + tid;
  s[tid] = deg[g]; __syncthreads();
  for(int off=1; off<256; off<<=1){
    int a = (tid>=off) ? s[tid-off] : 0; __syncthreads();
    s[tid] += a; __syncthreads();
  }
  offs[g+1] = s[tid];
  if(tid==255) bsums[blockIdx.x] = s[255];
}

__global__ void k_scan2(const int* __restrict__ bsums, int* __restrict__ boffs){
  __shared__ int s[128];
  int tid = threadIdx.x;
  int v = (tid<125) ? bsums[tid] : 0;
  s[tid] = v; __syncthreads();
  for(int off=1; off<128; off<<=1){
    int a = (tid>=off) ? s[tid-off] : 0; __syncthreads();
    s[tid] += a; __syncthreads();
  }
  if(tid<125) boffs[tid] = s[tid] - v;
}

__global__ void k_scan3(int* __restrict__ offs, const int* __restrict__ boffs){
  int tid = threadIdx.x; int g = blockIdx.x*256 + tid;
  offs[g+1] += boffs[blockIdx.x];
  if(g==0) offs[0]=0;
}

// csr stores LOCAL src index (all edges intra-graph) -> gat12 skips per-edge /N_
__global__ void k_scatter(const int* __restrict__ ei, const int* __restrict__ offs,
                          int* __restrict__ cursor, int* __restrict__ csr){
  int e = blockIdx.x*256 + threadIdx.x; if(e>=ETOT) return;
  int srcl, dst;
  if (e < B_*E_){ int b=e/E_; int k=e-b*E_; srcl=ei[k]; dst=ei[E_+k]+b*N_; }
  else { dst = e - B_*E_; int b=dst/N_; srcl = dst - b*N_; }
  int pos = atomicAdd(&cursor[dst], 1);
  csr[offs[dst]+pos] = srcl;
}

// ---------------- fused GAT1 + GAT2 feature/score ----------------
__global__ __launch_bounds__(256) void k_gat12(
  const float* __restrict__ x_seq, const float* __restrict__ W1,
  const float* __restrict__ as1, const float* __restrict__ ad1, const float* __restrict__ b1,
  const float* __restrict__ W2, const float* __restrict__ as2, const float* __restrict__ ad2,
  const int* __restrict__ offs, const int* __restrict__ csr,
  u16* __restrict__ h2u, float* __restrict__ asc, float* __restrict__ adc)
{
  __shared__ float W2s[2048];       // [k=32][c=64] fp32
  __shared__ float a2s[64], a2d[64];
  int tid = threadIdx.x;
  for(int i=tid;i<2048;i+=256) W2s[i]=W2[i];
  if(tid<64){ a2s[tid]=as2[tid]; a2d[tid]=ad2[tid]; }
  __syncthreads();

  int t = blockIdx.y;
  int id = blockIdx.x*256 + tid;     // 500*256 = M_*4
  int m = id>>2, l4 = id&3;

  float sS[4], sD[4];
  #pragma unroll
  for(int h=0;h<4;h++){
    float a=0.f, d=0.f;
    #pragma unroll
    for(int c=0;c<8;c++){ float w=W1[h*8+c]; a+=w*as1[h*8+c]; d+=w*ad1[h*8+c]; }
    sS[h]=a; sD[h]=d;
  }
  unsigned um=(unsigned)m, b=um/N_, n=um-b*N_;
  const float* xsl = x_seq + (size_t)(b*T_+t)*N_;
  float xm = xsl[n];
  int e0=offs[m], e1=offs[m+1];
  float sum[4]={0,0,0,0}, ax[4]={0,0,0,0};
  for(int e=e0+l4; e<e1; e+=4){
    float xv = xsl[csr[e]];           // csr holds local index
    #pragma unroll
    for(int h=0;h<4;h++){
      float ee = xv*sS[h] + xm*sD[h]; ee = ee>0.f ? ee : 0.2f*ee;
      float w = __expf(ee); sum[h]+=w; ax[h]+=w*xv;
    }
  }
  float A[4];
  #pragma unroll
  for(int h=0;h<4;h++){
    sum[h] += __shfl_xor(sum[h],1); sum[h] += __shfl_xor(sum[h],2);
    ax[h]  += __shfl_xor(ax[h],1);  ax[h]  += __shfl_xor(ax[h],2);
    A[h] = ax[h]/(sum[h]+1e-16f);
  }

  float acc[16];
  #pragma unroll
  for(int c=0;c<16;c++) acc[c]=0.f;
  #pragma unroll
  for(int k=0;k<32;k++){
    int hs = k>>3;
    float v = A[hs]*W1[k] + b1[k]; v = v>0.f ? v : 0.f;   // relu(out1)
    #pragma unroll
    for(int c=0;c<16;c++) acc[c] += v*W2s[k*64 + l4*16 + c];
  }
  uint2* hp = (uint2*)(h2u + ((size_t)t*M_ + m)*64 + l4*16);
  #pragma unroll
  for(int c2=0;c2<4;c2++){
    uint2 p;
    p.x = (unsigned)f2bu(acc[4*c2+0]) | ((unsigned)f2bu(acc[4*c2+1])<<16);
    p.y = (unsigned)f2bu(acc[4*c2+2]) | ((unsigned)f2bu(acc[4*c2+3])<<16);
    hp[c2] = p;
  }
  float ss=0.f, sd=0.f;
  #pragma unroll
  for(int c=0;c<16;c++){ ss += acc[c]*a2s[l4*16+c]; sd += acc[c]*a2d[l4*16+c]; }
  asc[((size_t)t*M_+m)*4+l4]=ss; adc[((size_t)t*M_+m)*4+l4]=sd;
}

// ---------------- GAT2 softmax-aggregate + bias + relu + PE(table); f16 out ------
__global__ __launch_bounds__(256) void k_gat2b(
  const u16* __restrict__ h2u, const float* __restrict__ asc, const float* __restrict__ adc,
  const float* __restrict__ b2, const int* __restrict__ offs, const int* __restrict__ csr,
  const float* __restrict__ peT, u16* __restrict__ seq)
{
  int t = blockIdx.y;
  int id = blockIdx.x*256 + threadIdx.x;
  int m = id>>2, h = id&3;
  unsigned um=(unsigned)m, b=um/N_;
  size_t base_s = (size_t)t*M_ + (size_t)b*N_;   // csr holds local indices
  float am = adc[((size_t)t*M_+m)*4+h];
  int e0=offs[m], e1=offs[m+1];
  float sum=0.f;
  float A[16];
  #pragma unroll
  for(int c=0;c<16;c++) A[c]=0.f;
  for(int e=e0;e<e1;e++){
    size_t s = base_s + (unsigned)csr[e];
    float ee = asc[s*4+h] + am; ee = ee>0.f ? ee : 0.2f*ee;
    float w = __expf(ee); sum += w;
    const uint2* hp = (const uint2*)(h2u + s*64 + h*16);
    #pragma unroll
    for(int c2=0;c2<4;c2++){
      uint2 p = hp[c2];
      A[4*c2+0] += w*bfu((u16)(p.x));
      A[4*c2+1] += w*bfu((u16)(p.x>>16));
      A[4*c2+2] += w*bfu((u16)(p.y));
      A[4*c2+3] += w*bfu((u16)(p.y>>16));
    }
  }
  float inv = 1.f/(sum + 1e-16f);
  #pragma unroll
  for(int c=0;c<16;c++){
    int ch = h*16 + c;
    float v = A[c]*inv + b2[ch]; v = v>0.f ? v : 0.f;
    seq[((size_t)t*M_ + m)*64 + ch] = f2h(v + peT[t*64+ch]);
  }
}

// ---------------- BOTH transformer layers, transposed-MFMA outputs ----------------
// Operand swap (A=weights, B=activations; A/B lane layouts are identical for
// 16x16x32): D comes out [out_ch][data_row], so lane (q,m) holds 4 CONSECUTIVE
// channels of row m -> every LDS scatter is one packed uint2 (b64) write
// (112 -> 28 writes/lane/layer) and LN reduces across quads with 2 shuffles.
__global__ __launch_bounds__(192) void k_layer2(
  u16* __restrict__ seq,
  const u16* __restrict__ wqB, const u16* __restrict__ woB,
  const u16* __restrict__ w1B, const u16* __restrict__ w2B,
  const float* __restrict__ bqkv, const float* __restrict__ bo,
  const float* __restrict__ bf1,  const float* __restrict__ bf2,
  const float* __restrict__ g1,   const float* __restrict__ be1,
  const float* __restrict__ g2,   const float* __restrict__ be2)
{
  __shared__ __align__(16) u16 X[3456];      // [48][72] f16
  __shared__ __align__(16) u16 QKV[10368];   // [3][48][72]
  u16* Hd = QKV + 3456;                      // H[48][136] overlays K,V
  int tid=threadIdx.x, w=tid>>6, lane=tid&63;
  int m=lane&15, q=lane>>4;
  int r = w*16 + m;                          // this lane's data row (A and D!)
  int nr = r/12, tr = r - nr*12;
  int node_r = blockIdx.x*4 + nr;
  size_t xoff = ((size_t)tr*M_ + node_r)*64; // global offset of row r

  // stage X: wave w loads its own 16 rows (wave-private)
  #pragma unroll
  for(int rr=0; rr<16; rr++){
    int row = w*16+rr;
    int nn = row/12, tt = row-nn*12;
    X[row*72+lane] = seq[((size_t)tt*M_ + (size_t)blockIdx.x*4+nn)*64 + lane];
  }

  #pragma unroll 1
  for(int l=0; l<2; l++){
    const half8* wqv = (const half8*)(wqB + (size_t)l*12288);
    const half8* wov = (const half8*)(woB + (size_t)l*4096);
    const half8* w1v = (const half8*)(w1B + (size_t)l*8192);
    const half8* w2v = (const half8*)(w2B + (size_t)l*8192);
    const float* bq = bqkv + l*192;
    const float* boL = bo + l*64;
    const float* b1L = bf1 + l*128;
    const float* b2L = bf2 + l*64;
    const float* g1L = g1 + l*64, *be1L = be1 + l*64;
    const float* g2L = g2 + l*64, *be2L = be2 + l*64;

    // ---- QKV projection: B = X rows, A = weights; D[ch][row] ----
    half8 xb0 = *(const half8*)&X[r*72 + q*8];
    half8 xb1 = *(const half8*)&X[r*72 + 32 + q*8];
    #pragma unroll
    for(int nt=0; nt<12; nt++){
      f32x4 acc={0.f,0.f,0.f,0.f};
      acc = __builtin_amdgcn_mfma_f32_16x16x32_f16(wqv[(nt*2+0)*64+lane], xb0, acc,0,0,0);
      acc = __builtin_amdgcn_mfma_f32_16x16x32_f16(wqv[(nt*2+1)*64+lane], xb1, acc,0,0,0);
      int cg0 = nt*16 + q*4;                 // 4 consecutive qkv channels
      float4 bv = *(const float4*)&bq[cg0];
      int s = cg0>>6, lc = cg0&63;
      uint2 pk;
      pk.x = pk2(acc[0]+bv.x, acc[1]+bv.y);
      pk.y = pk2(acc[2]+bv.z, acc[3]+bv.w);
      *(uint2*)&QKV[s*3456 + r*72 + lc] = pk;
    }
    __syncthreads();

    // ---- attention: 192 lanes = (node an, head ah, time at); fdot2 + pk_fma ----
    {
      int an = tid/48, rem = tid - an*48;
      int ah = rem/12, at = rem - ah*12;
      u16* qrow = &QKV[(an*12+at)*72 + ah*16];
      uint4 qa = ((const uint4*)qrow)[0], qb = ((const uint4*)qrow)[1];
      float s[12];
      #pragma unroll
      for(int t2=0;t2<12;t2++){
        const uint4* kp = (const uint4*)&QKV[3456 + (an*12+t2)*72 + ah*16];
        uint4 ka=kp[0], kb=kp[1];
        float d=0.f;
        d=__builtin_amdgcn_fdot2(u2h(qa.x),u2h(ka.x),d,false);
        d=__builtin_amdgcn_fdot2(u2h(qa.y),u2h(ka.y),d,false);
        d=__builtin_amdgcn_fdot2(u2h(qa.z),u2h(ka.z),d,false);
        d=__builtin_amdgcn_fdot2(u2h(qa.w),u2h(ka.w),d,false);
        d=__builtin_amdgcn_fdot2(u2h(qb.x),u2h(kb.x),d,false);
        d=__builtin_amdgcn_fdot2(u2h(qb.y),u2h(kb.y),d,false);
        d=__builtin_amdgcn_fdot2(u2h(qb.z),u2h(kb.z),d,false);
        d=__builtin_amdgcn_fdot2(u2h(qb.w),u2h(kb.w),d,false);
        s[t2] = d*0.25f;
      }
      float mx=s[0];
      #pragma unroll
      for(int t2=1;t2<12;t2++) mx=fmaxf(mx,s[t2]);
      float sum=0.f;
      #pragma unroll
      for(int t2=0;t2<12;t2++){ s[t2]=__expf(s[t2]-mx); sum+=s[t2]; }
      float inv=1.f/sum;
      half8 o0, o1;
      #pragma unroll
      for(int i=0;i<8;i++){ o0[i]=(_Float16)0.f; o1[i]=(_Float16)0.f; }
      #pragma unroll
      for(int t2=0;t2<12;t2++){
        const half8* vr = (const half8*)&QKV[6912 + (an*12+t2)*72 + ah*16];
        _Float16 wh = (_Float16)s[t2];
        o0 += vr[0]*wh; o1 += vr[1]*wh;
      }
      _Float16 ih = (_Float16)inv;
      ((half8*)qrow)[0]=o0*ih; ((half8*)qrow)[1]=o1*ih;
    }
    __syncthreads();

    // ---- Wo + residual(X) + LN1; D[ch][row] ----
    half8 ob0 = *(const half8*)&QKV[r*72 + q*8];
    half8 ob1 = *(const half8*)&QKV[r*72 + 32 + q*8];
    float y[4][4];                 // [nt][rg] = channel nt*16+q*4+rg of row r
    #pragma unroll
    for(int nt=0;nt<4;nt++){
      f32x4 acc={0.f,0.f,0.f,0.f};
      acc = __builtin_amdgcn_mfma_f32_16x16x32_f16(wov[(nt*2+0)*64+lane], ob0, acc,0,0,0);
      acc = __builtin_amdgcn_mfma_f32_16x16x32_f16(wov[(nt*2+1)*64+lane], ob1, acc,0,0,0);
      int ch0=nt*16+q*4;
      float4 bv = *(const float4*)&boL[ch0];
      uint2 xr_ = *(const uint2*)&X[r*72 + ch0];
      h2v x0=u2h(xr_.x), x1=u2h(xr_.y);
      y[nt][0] = acc[0] + bv.x + (float)x0[0];
      y[nt][1] = acc[1] + bv.y + (float)x0[1];
      y[nt][2] = acc[2] + bv.z + (float)x1[0];
      y[nt][3] = acc[3] + bv.w + (float)x1[1];
    }
    // LN over channels of row r: local 16-sum + reduce across quads (2 shuffles)
    float sm=0.f;
    #pragma unroll
    for(int nt=0;nt<4;nt++) sm += (y[nt][0]+y[nt][1])+(y[nt][2]+y[nt][3]);
    sm += __shfl_xor(sm,16); sm += __shfl_xor(sm,32);
    float mu = sm*(1.f/64.f);
    float vv=0.f;
    #pragma unroll
    for(int nt=0;nt<4;nt++){
      float d0=y[nt][0]-mu, d1=y[nt][1]-mu, d2=y[nt][2]-mu, d3=y[nt][3]-mu;
      vv += (d0*d0+d1*d1)+(d2*d2+d3*d3);
    }
    vv += __shfl_xor(vv,16); vv += __shfl_xor(vv,32);
    float rs = rsqrtf(vv*(1.f/64.f)+1e-5f);
    #pragma unroll
    for(int nt=0;nt<4;nt++){
      int ch0=nt*16+q*4;
      float4 gv = *(const float4*)&g1L[ch0];
      float4 bev= *(const float4*)&be1L[ch0];
      y[nt][0]=(y[nt][0]-mu)*rs*gv.x+bev.x;
      y[nt][1]=(y[nt][1]-mu)*rs*gv.y+bev.y;
      y[nt][2]=(y[nt][2]-mu)*rs*gv.z+bev.z;
      y[nt][3]=(y[nt][3]-mu)*rs*gv.w+bev.w;
      uint2 pk; pk.x=pk2(y[nt][0],y[nt][1]); pk.y=pk2(y[nt][2],y[nt][3]);
      *(uint2*)&QKV[r*72 + ch0] = pk;      // y -> Q region, wave-own row
    }

    // ---- FF1: B = y rows; D[hc][row] -> Hd packed writes ----
    half8 yb0 = *(const half8*)&QKV[r*72 + q*8];
    half8 yb1 = *(const half8*)&QKV[r*72 + 32 + q*8];
    #pragma unroll
    for(int nt=0;nt<8;nt++){
      f32x4 acc={0.f,0.f,0.f,0.f};
      acc = __builtin_amdgcn_mfma_f32_16x16x32_f16(w1v[(nt*2+0)*64+lane], yb0, acc,0,0,0);
      acc = __builtin_amdgcn_mfma_f32_16x16x32_f16(w1v[(nt*2+1)*64+lane], yb1, acc,0,0,0);
      int hc0=nt*16+q*4;
      float4 bv = *(const float4*)&b1L[hc0];
      uint2 pk;
      pk.x = pk2(fmaxf(acc[0]+bv.x,0.f), fmaxf(acc[1]+bv.y,0.f));
      pk.y = pk2(fmaxf(acc[2]+bv.z,0.f), fmaxf(acc[3]+bv.w,0.f));
      *(uint2*)&Hd[r*136 + hc0] = pk;
    }

    // ---- FF2: B = H rows; D[ch][row]; + residual y + LN2 ----
    half8 hb[4];
    #pragma unroll
    for(int c=0;c<4;c++)
      hb[c] = *(const half8*)&Hd[r*136 + c*32 + q*8];
    #pragma unroll
    for(int nt=0;nt<4;nt++){
      f32x4 acc={0.f,0.f,0.f,0.f};
      #pragma unroll
      for(int c=0;c<4;c++)
        acc = __builtin_amdgcn_mfma_f32_16x16x32_f16(w2v[(nt*4+c)*64+lane], hb[c], acc,0,0,0);
      int ch0=nt*16+q*4;
      float4 bv = *(const float4*)&b2L[ch0];
      y[nt][0] = acc[0] + bv.x + y[nt][0];
      y[nt][1] = acc[1] + bv.y + y[nt][1];
      y[nt][2] = acc[2] + bv.z + y[nt][2];
      y[nt][3] = acc[3] + bv.w + y[nt][3];
    }
    sm=0.f;
    #pragma unroll
    for(int nt=0;nt<4;nt++) sm += (y[nt][0]+y[nt][1])+(y[nt][2]+y[nt][3]);
    sm += __shfl_xor(sm,16); sm += __shfl_xor(sm,32);
    mu = sm*(1.f/64.f);
    vv=0.f;
    #pragma unroll
    for(int nt=0;nt<4;nt++){
      float d0=y[nt][0]-mu, d1=y[nt][1]-mu, d2=y[nt][2]-mu, d3=y[nt][3]-mu;
      vv += (d0*d0+d1*d1)+(d2*d2+d3*d3);
    }
    vv += __shfl_xor(vv,16); vv += __shfl_xor(vv,32);
    rs = rsqrtf(vv*(1.f/64.f)+1e-5f);
    if(l==0){
      #pragma unroll
      for(int nt=0;nt<4;nt++){
        int ch0=nt*16+q*4;
        float4 gv = *(const float4*)&g2L[ch0];
        float4 bev= *(const float4*)&be2L[ch0];
        uint2 pk;
        pk.x = pk2((y[nt][0]-mu)*rs*gv.x+bev.x, (y[nt][1]-mu)*rs*gv.y+bev.y);
        pk.y = pk2((y[nt][2]-mu)*rs*gv.z+bev.z, (y[nt][3]-mu)*rs*gv.w+bev.w);
        *(uint2*)&X[r*72 + ch0] = pk;      // layer-0 out -> X, wave-own row
      }
      __syncthreads();   // before next layer's QKV scatter overwrites QKV
    } else {
      if(tr==11){
        #pragma unroll
        for(int nt=0;nt<4;nt++){
          int ch0=nt*16+q*4;
          float4 gv = *(const float4*)&g2L[ch0];
          float4 bev= *(const float4*)&be2L[ch0];
          uint2 pk;
          pk.x = pk2((y[nt][0]-mu)*rs*gv.x+bev.x, (y[nt][1]-mu)*rs*gv.y+bev.y);
          pk.y = pk2((y[nt][2]-mu)*rs*gv.z+bev.z, (y[nt][3]-mu)*rs*gv.w+bev.w);
          *(uint2*)&seq[xoff + ch0] = pk;
        }
      }
    }
  }
}

// ---------------- prediction head (f16 seq in) ----------------
__global__ void k_head(const u16* __restrict__ seq, const float* __restrict__ Wh,
                       const float* __restrict__ bh, float* __restrict__ out){
  int m = blockIdx.x*256 + threadIdx.x; if(m>=M_) return;
  const u16* row = seq + ((size_t)11*M_ + m)*64;
  float a0=bh[0], a1=bh[1], a2=bh[2];
  #pragma unroll
  for(int d=0;d<64;d++){
    float x = h2f(row[d]);
    a0 += x*Wh[d]; a1 += x*Wh[64+d]; a2 += x*Wh[128+d];
  }
  unsigned b=(unsigned)m/N_, n=(unsigned)m-b*N_;
  out[(b*3+0)*N_+n] = a0;
  out[(b*3+1)*N_+n] = a1;
  out[(b*3+2)*N_+n] = a2;
}

extern "C" void kernel_launch(void* const* d_in, const int* in_sizes, int n_in,
                              void* d_out, int out_size, void* d_ws, size_t ws_size,
                              hipStream_t stream)
{
  const float* x_seq=(const float*)d_in[0];
  const int*   ei   =(const int*)d_in[1];
  const float* W1   =(const float*)d_in[2];
  const float* as1  =(const float*)d_in[3];
  const float* ad1  =(const float*)d_in[4];
  const float* b1   =(const float*)d_in[5];
  const float* W2   =(const float*)d_in[6];
  const float* as2  =(const float*)d_in[7];
  const float* ad2  =(const float*)d_in[8];
  const float* b2   =(const float*)d_in[9];
  const float* Wqkv =(const float*)d_in[10];
  const float* bqkv =(const float*)d_in[11];
  const float* Wo   =(const float*)d_in[12];
  const float* bo   =(const float*)d_in[13];
  const float* Wf1  =(const float*)d_in[14];
  const float* bf1p =(const float*)d_in[15];
  const float* Wf2  =(const float*)d_in[16];
  const float* bf2p =(const float*)d_in[17];
  const float* g1   =(const float*)d_in[18];
  const float* be1  =(const float*)d_in[19];
  const float* g2   =(const float*)d_in[20];
  const float* be2  =(const float*)d_in[21];
  const float* Wh   =(const float*)d_in[22];
  const float* bh   =(const float*)d_in[23];

  // workspace layout (~112 MB)
  u16* seqh   = (u16*)d_ws;                     // [T][M][64] f16  24,576,000 u16
  float* asc  = (float*)(seqh + 24576000);      // [T][M][4]        1,536,000 f
  float* adc  = asc + 1536000;                  //                  1,536,000 f
  int* deg    = (int*)(adc + 1536000);
  int* cursor = deg + M_;
  int* offs   = cursor + M_;                    // M_+1 used
  int* bsums  = offs + (M_ + 2);
  int* boffs  = bsums + 128;
  int* csr    = boffs + 128;                    // ETOT
  u16* h2u    = (u16*)(csr + ETOT);             // [T][M][64]   24,576,000 u16
  u16* wqB    = h2u + (size_t)T_*M_*64;         // 24576
  u16* woB    = wqB + 24576;                    // 8192
  u16* w1B    = woB + 8192;                     // 16384
  u16* w2B    = w1B + 16384;                    // 16384
  float* peT  = (float*)(w2B + 16384);          // 768

  k_prep   <<<dim3(260), dim3(256), 0, stream>>>(Wqkv, Wo, Wf1, Wf2, wqB, woB, w1B, w2B, peT);

  // CSR build (edge list identical for all t)
  hipMemsetAsync(deg, 0, (size_t)2*M_*sizeof(int), stream);   // deg + cursor
  k_hist   <<<dim3((ETOT+255)/256), dim3(256), 0, stream>>>(ei, deg);
  k_scan1  <<<dim3(125), dim3(256), 0, stream>>>(deg, offs, bsums);
  k_scan2  <<<dim3(1),   dim3(128), 0, stream>>>(bsums, boffs);
  k_scan3  <<<dim3(125), dim3(256), 0, stream>>>(offs, boffs);
  k_scatter<<<dim3((ETOT+255)/256), dim3(256), 0, stream>>>(ei, offs, cursor, csr);

  k_gat12<<<dim3(500,T_), dim3(256), 0, stream>>>(x_seq, W1, as1, ad1, b1,
                                                  W2, as2, ad2, offs, csr, h2u, asc, adc);
  k_gat2b<<<dim3(500,T_), dim3(256), 0, stream>>>(h2u, asc, adc, b2, offs, csr, peT, seqh);

  k_layer2<<<dim3(8000), dim3(192), 0, stream>>>(seqh,
      wqB, woB, w1B, w2B,
      bqkv, bo, bf1p, bf2p,
      g1, be1, g2, be2);

  k_head<<<dim3(125), dim3(256), 0, stream>>>(seqh, Wh, bh, (float*)d_out);
}

// Round 18
// 411.363 us; speedup vs baseline: 1.0220x; 1.0220x over previous
//
#include <hip/hip_runtime.h>
#include <hip/hip_bf16.h>

#define B_ 16
#define T_ 12
#define N_ 2000
#define E_ 8000
#define M_ 32000                 // B_*N_
#define ETOT (B_*E_ + M_)        // 160000 edges incl. self loops
#define D_ 64

typedef __hip_bfloat16 bf16;
typedef unsigned short u16;
typedef __attribute__((ext_vector_type(8))) _Float16 half8;
typedef __attribute__((ext_vector_type(2))) _Float16 h2v;
typedef __attribute__((ext_vector_type(4))) float f32x4;

__device__ __forceinline__ float bfu(u16 u){ return __uint_as_float(((unsigned int)u)<<16); }
__device__ __forceinline__ u16 f2bu(float f){
  unsigned int x = __float_as_uint(f);
  x += 0x7FFFu + ((x >> 16) & 1u);
  return (u16)(x >> 16);
}
__device__ __forceinline__ u16 f2h(float f){
  _Float16 h = (_Float16)f; u16 r; __builtin_memcpy(&r, &h, 2); return r;
}
__device__ __forceinline__ float h2f(u16 u){
  _Float16 h; __builtin_memcpy(&h, &u, 2); return (float)h;
}
__device__ __forceinline__ h2v u2h(unsigned u){ h2v r; __builtin_memcpy(&r,&u,4); return r; }

// ---------------- weight prep: f16 MFMA B-fragments + PE table ----------------
__global__ void k_prep(const float* __restrict__ Wqkv, const float* __restrict__ Wo,
                       const float* __restrict__ Wf1, const float* __restrict__ Wf2,
                       u16* __restrict__ wqB, u16* __restrict__ woB,
                       u16* __restrict__ w1B, u16* __restrict__ w2B,
                       float* __restrict__ peT){
  int i = blockIdx.x*256 + threadIdx.x;    // 260 blocks
  if(i < 24576){
    int l=i/12288, r=i-l*12288;
    int nt=r>>10, r2=r&1023, c=r2>>9, r3=r2&511, lane=r3>>3, jj=r3&7;
    int m=lane&15, q=lane>>4;
    wqB[i] = f2h(Wqkv[l*12288 + (nt*16+m)*64 + c*32 + q*8 + jj]);
  } else if(i < 32768){
    int k2=i-24576;
    int l=k2>>12, r=k2&4095;
    int nt=r>>10, r2=r&1023, c=r2>>9, r3=r2&511, lane=r3>>3, jj=r3&7;
    int m=lane&15, q=lane>>4;
    woB[k2] = f2h(Wo[l*4096 + (nt*16+m)*64 + c*32 + q*8 + jj]);
  } else if(i < 49152){
    int k2=i-32768;
    int l=k2>>13, r=k2&8191;
    int nt=r>>10, r2=r&1023, c=r2>>9, r3=r2&511, lane=r3>>3, jj=r3&7;
    int m=lane&15, q=lane>>4;
    w1B[k2] = f2h(Wf1[l*8192 + (nt*16+m)*64 + c*32 + q*8 + jj]);
  } else if(i < 65536){
    int k2=i-49152;
    int l=k2>>13, r=k2&8191;
    int nt=r>>11, r2=r&2047, c=r2>>9, r3=r2&511, lane=r3>>3, jj=r3&7;
    int m=lane&15, q=lane>>4;
    w2B[k2] = f2h(Wf2[l*8192 + (nt*16+m)*128 + c*32 + q*8 + jj]);
  } else {
    int i2 = i - 65536;
    if(i2 < 768){
      int t=i2>>6, ch=i2&63;
      float ang = (float)t * __expf(-0.14391156463f * (float)(ch & ~1));
      peT[i2] = (ch&1) ? __cosf(ang) : __sinf(ang);
    }
  }
}

// ---------------- CSR build ----------------
__global__ void k_hist(const int* __restrict__ ei, int* __restrict__ deg){
  int e = blockIdx.x*256 + threadIdx.x; if(e>=ETOT) return;
  int dst;
  if (e < B_*E_){ int b = e / E_; int k = e - b*E_; dst = ei[E_ + k] + b*N_; }
  else dst = e - B_*E_;
  atomicAdd(&deg[dst], 1);
}

__global__ void k_scan1(const int* __restrict__ deg, int* __restrict__ offs, int* __restrict__ bsums){
  __shared__ int s[256];
  int tid = threadIdx.x; int g = blockIdx.x*256 + tid;
  s[tid] = deg[g]; __syncthreads();
  for(int off=1; off<256; off<<=1){
    int a = (tid>=off) ? s[tid-off] : 0; __syncthreads();
    s[tid] += a; __syncthreads();
  }
  offs[g+1] = s[tid];
  if(tid==255) bsums[blockIdx.x] = s[255];
}

__global__ void k_scan2(const int* __restrict__ bsums, int* __restrict__ boffs){
  __shared__ int s[128];
  int tid = threadIdx.x;
  int v = (tid<125) ? bsums[tid] : 0;
  s[tid] = v; __syncthreads();
  for(int off=1; off<128; off<<=1){
    int a = (tid>=off) ? s[tid-off] : 0; __syncthreads();
    s[tid] += a; __syncthreads();
  }
  if(tid<125) boffs[tid] = s[tid] - v;
}

__global__ void k_scan3(int* __restrict__ offs, const int* __restrict__ boffs){
  int tid = threadIdx.x; int g = blockIdx.x*256 + tid;
  offs[g+1] += boffs[blockIdx.x];
  if(g==0) offs[0]=0;
}

// csr stores LOCAL src index (all edges intra-graph) -> gat kernels skip /N_
__global__ void k_scatter(const int* __restrict__ ei, const int* __restrict__ offs,
                          int* __restrict__ cursor, int* __restrict__ csr){
  int e = blockIdx.x*256 + threadIdx.x; if(e>=ETOT) return;
  int srcl, dst;
  if (e < B_*E_){ int b=e/E_; int k=e-b*E_; srcl=ei[k]; dst=ei[E_+k]+b*N_; }
  else { dst = e - B_*E_; int b=dst/N_; srcl = dst - b*N_; }
  int pos = atomicAdd(&cursor[dst], 1);
  csr[offs[dst]+pos] = srcl;
}

// ---------------- fused GAT1 + GAT2 feature/score ----------------
__global__ __launch_bounds__(256) void k_gat12(
  const float* __restrict__ x_seq, const float* __restrict__ W1,
  const float* __restrict__ as1, const float* __restrict__ ad1, const float* __restrict__ b1,
  const float* __restrict__ W2, const float* __restrict__ as2, const float* __restrict__ ad2,
  const int* __restrict__ offs, const int* __restrict__ csr,
  u16* __restrict__ h2u, float* __restrict__ asc, float* __restrict__ adc)
{
  __shared__ float W2s[2048];       // [k=32][c=64] fp32
  __shared__ float a2s[64], a2d[64];
  int tid = threadIdx.x;
  for(int i=tid;i<2048;i+=256) W2s[i]=W2[i];
  if(tid<64){ a2s[tid]=as2[tid]; a2d[tid]=ad2[tid]; }
  __syncthreads();

  int t = blockIdx.y;
  int id = blockIdx.x*256 + tid;     // 500*256 = M_*4
  int m = id>>2, l4 = id&3;

  float sS[4], sD[4];
  #pragma unroll
  for(int h=0;h<4;h++){
    float a=0.f, d=0.f;
    #pragma unroll
    for(int c=0;c<8;c++){ float w=W1[h*8+c]; a+=w*as1[h*8+c]; d+=w*ad1[h*8+c]; }
    sS[h]=a; sD[h]=d;
  }
  unsigned um=(unsigned)m, b=um/N_, n=um-b*N_;
  const float* xsl = x_seq + (size_t)(b*T_+t)*N_;
  float xm = xsl[n];
  int e0=offs[m], e1=offs[m+1];
  float sum[4]={0,0,0,0}, ax[4]={0,0,0,0};
  for(int e=e0+l4; e<e1; e+=4){
    float xv = xsl[csr[e]];           // csr holds local index
    #pragma unroll
    for(int h=0;h<4;h++){
      float ee = xv*sS[h] + xm*sD[h]; ee = ee>0.f ? ee : 0.2f*ee;
      float w = __expf(ee); sum[h]+=w; ax[h]+=w*xv;
    }
  }
  float A[4];
  #pragma unroll
  for(int h=0;h<4;h++){
    sum[h] += __shfl_xor(sum[h],1); sum[h] += __shfl_xor(sum[h],2);
    ax[h]  += __shfl_xor(ax[h],1);  ax[h]  += __shfl_xor(ax[h],2);
    A[h] = ax[h]/(sum[h]+1e-16f);
  }

  float acc[16];
  #pragma unroll
  for(int c=0;c<16;c++) acc[c]=0.f;
  #pragma unroll
  for(int k=0;k<32;k++){
    int hs = k>>3;
    float v = A[hs]*W1[k] + b1[k]; v = v>0.f ? v : 0.f;   // relu(out1)
    #pragma unroll
    for(int c=0;c<16;c++) acc[c] += v*W2s[k*64 + l4*16 + c];
  }
  uint2* hp = (uint2*)(h2u + ((size_t)t*M_ + m)*64 + l4*16);
  #pragma unroll
  for(int c2=0;c2<4;c2++){
    uint2 p;
    p.x = (unsigned)f2bu(acc[4*c2+0]) | ((unsigned)f2bu(acc[4*c2+1])<<16);
    p.y = (unsigned)f2bu(acc[4*c2+2]) | ((unsigned)f2bu(acc[4*c2+3])<<16);
    hp[c2] = p;
  }
  float ss=0.f, sd=0.f;
  #pragma unroll
  for(int c=0;c<16;c++){ ss += acc[c]*a2s[l4*16+c]; sd += acc[c]*a2d[l4*16+c]; }
  asc[((size_t)t*M_+m)*4+l4]=ss; adc[((size_t)t*M_+m)*4+l4]=sd;
}

// ---------------- GAT2 softmax-aggregate + bias + relu + PE(table); f16 out ------
__global__ __launch_bounds__(256) void k_gat2b(
  const u16* __restrict__ h2u, const float* __restrict__ asc, const float* __restrict__ adc,
  const float* __restrict__ b2, const int* __restrict__ offs, const int* __restrict__ csr,
  const float* __restrict__ peT, u16* __restrict__ seq)
{
  int t = blockIdx.y;
  int id = blockIdx.x*256 + threadIdx.x;
  int m = id>>2, h = id&3;
  unsigned um=(unsigned)m, b=um/N_;
  size_t base_s = (size_t)t*M_ + (size_t)b*N_;   // csr holds local indices
  float am = adc[((size_t)t*M_+m)*4+h];
  int e0=offs[m], e1=offs[m+1];
  float sum=0.f;
  float A[16];
  #pragma unroll
  for(int c=0;c<16;c++) A[c]=0.f;
  for(int e=e0;e<e1;e++){
    size_t s = base_s + (unsigned)csr[e];
    float ee = asc[s*4+h] + am; ee = ee>0.f ? ee : 0.2f*ee;
    float w = __expf(ee); sum += w;
    const uint2* hp = (const uint2*)(h2u + s*64 + h*16);
    #pragma unroll
    for(int c2=0;c2<4;c2++){
      uint2 p = hp[c2];
      A[4*c2+0] += w*bfu((u16)(p.x));
      A[4*c2+1] += w*bfu((u16)(p.x>>16));
      A[4*c2+2] += w*bfu((u16)(p.y));
      A[4*c2+3] += w*bfu((u16)(p.y>>16));
    }
  }
  float inv = 1.f/(sum + 1e-16f);
  #pragma unroll
  for(int c=0;c<16;c++){
    int ch = h*16 + c;
    float v = A[c]*inv + b2[ch]; v = v>0.f ? v : 0.f;
    seq[((size_t)t*M_ + m)*64 + ch] = f2h(v + peT[t*64+ch]);
  }
}

// ---------------- BOTH transformer layers in one kernel (R16-measured form) -------
// X u16 [48][72]: layer input (wave-private rows). QKV u16 [3][48][72]; K,V
// overlaid by H[48][136]. A = activations (standard orientation; the R17
// operand-swap tripled LDS bank conflicts and regressed). Layer-0 out -> X;
// layer-1 stores only t=11 rows.
__global__ __launch_bounds__(192) void k_layer2(
  u16* __restrict__ seq,
  const u16* __restrict__ wqB, const u16* __restrict__ woB,
  const u16* __restrict__ w1B, const u16* __restrict__ w2B,
  const float* __restrict__ bqkv, const float* __restrict__ bo,
  const float* __restrict__ bf1,  const float* __restrict__ bf2,
  const float* __restrict__ g1,   const float* __restrict__ be1,
  const float* __restrict__ g2,   const float* __restrict__ be2)
{
  __shared__ __align__(16) u16 X[3456];      // [48][72] f16
  __shared__ __align__(16) u16 QKV[10368];   // [3][48][72]
  u16* Hd = QKV + 3456;                      // H[48][136] overlays K,V
  int tid=threadIdx.x, w=tid>>6, lane=tid&63;
  int m=lane&15, q=lane>>4;
  int r = w*16 + m;

  int trr[4]; size_t base_rr[4];
  #pragma unroll
  for(int rg=0;rg<4;rg++){
    int rc = w*16 + q*4 + rg;
    int nn = rc/12; trr[rg] = rc - nn*12;
    base_rr[rg] = ((size_t)trr[rg]*M_ + (size_t)blockIdx.x*4 + nn)*64;
  }

  // stage X: wave w loads its own 16 rows (wave-private, no barrier needed)
  #pragma unroll
  for(int rr=0; rr<16; rr++){
    int row = w*16+rr;
    int nn = row/12, tt = row-nn*12;
    X[row*72+lane] = seq[((size_t)tt*M_ + (size_t)blockIdx.x*4+nn)*64 + lane];
  }

  #pragma unroll 1
  for(int l=0; l<2; l++){
    const half8* wqv = (const half8*)(wqB + (size_t)l*12288);
    const half8* wov = (const half8*)(woB + (size_t)l*4096);
    const half8* w1v = (const half8*)(w1B + (size_t)l*8192);
    const half8* w2v = (const half8*)(w2B + (size_t)l*8192);
    const float* bq = bqkv + l*192;
    const float* boL = bo + l*64;
    const float* b1L = bf1 + l*128;
    const float* b2L = bf2 + l*64;
    const float* g1L = g1 + l*64, *be1L = be1 + l*64;
    const float* g2L = g2 + l*64, *be2L = be2 + l*64;

    // ---- QKV projection: A-frags from X (wave-own rows) ----
    half8 xa0 = *(const half8*)&X[r*72 + q*8];
    half8 xa1 = *(const half8*)&X[r*72 + 32 + q*8];
    #pragma unroll
    for(int nt=0; nt<12; nt++){
      f32x4 acc={0.f,0.f,0.f,0.f};
      acc = __builtin_amdgcn_mfma_f32_16x16x32_f16(xa0, wqv[(nt*2+0)*64+lane], acc,0,0,0);
      acc = __builtin_amdgcn_mfma_f32_16x16x32_f16(xa1, wqv[(nt*2+1)*64+lane], acc,0,0,0);
      int cg = nt*16+m; float bias = bq[cg];
      int s = nt>>2, lc = cg&63;
      #pragma unroll
      for(int rg=0;rg<4;rg++){
        int row = w*16 + q*4 + rg;
        QKV[s*3456 + row*72 + lc] = f2h(acc[rg]+bias);
      }
    }
    __syncthreads();

    // ---- attention: 192 lanes = (node an, head ah, time at); fdot2 + pk_fma ----
    {
      int an = tid/48, rem = tid - an*48;
      int ah = rem/12, at = rem - ah*12;
      u16* qrow = &QKV[(an*12+at)*72 + ah*16];
      uint4 qa = ((const uint4*)qrow)[0], qb = ((const uint4*)qrow)[1];
      float s[12];
      #pragma unroll
      for(int t2=0;t2<12;t2++){
        const uint4* kp = (const uint4*)&QKV[3456 + (an*12+t2)*72 + ah*16];
        uint4 ka=kp[0], kb=kp[1];
        float d=0.f;
        d=__builtin_amdgcn_fdot2(u2h(qa.x),u2h(ka.x),d,false);
        d=__builtin_amdgcn_fdot2(u2h(qa.y),u2h(ka.y),d,false);
        d=__builtin_amdgcn_fdot2(u2h(qa.z),u2h(ka.z),d,false);
        d=__builtin_amdgcn_fdot2(u2h(qa.w),u2h(ka.w),d,false);
        d=__builtin_amdgcn_fdot2(u2h(qb.x),u2h(kb.x),d,false);
        d=__builtin_amdgcn_fdot2(u2h(qb.y),u2h(kb.y),d,false);
        d=__builtin_amdgcn_fdot2(u2h(qb.z),u2h(kb.z),d,false);
        d=__builtin_amdgcn_fdot2(u2h(qb.w),u2h(kb.w),d,false);
        s[t2] = d*0.25f;
      }
      float mx=s[0];
      #pragma unroll
      for(int t2=1;t2<12;t2++) mx=fmaxf(mx,s[t2]);
      float sum=0.f;
      #pragma unroll
      for(int t2=0;t2<12;t2++){ s[t2]=__expf(s[t2]-mx); sum+=s[t2]; }
      float inv=1.f/sum;
      half8 o0, o1;
      #pragma unroll
      for(int i=0;i<8;i++){ o0[i]=(_Float16)0.f; o1[i]=(_Float16)0.f; }
      #pragma unroll
      for(int t2=0;t2<12;t2++){
        const half8* vr = (const half8*)&QKV[6912 + (an*12+t2)*72 + ah*16];
        _Float16 wh = (_Float16)s[t2];
        o0 += vr[0]*wh; o1 += vr[1]*wh;
      }
      _Float16 ih = (_Float16)inv;
      ((half8*)qrow)[0]=o0*ih; ((half8*)qrow)[1]=o1*ih;
    }
    __syncthreads();

    // ---- Wo + residual(X) + LN1 ----
    half8 oa0 = *(const half8*)&QKV[r*72 + q*8];
    half8 oa1 = *(const half8*)&QKV[r*72 + 32 + q*8];
    float y[4][4];
    #pragma unroll
    for(int nt=0;nt<4;nt++){
      f32x4 acc={0.f,0.f,0.f,0.f};
      acc = __builtin_amdgcn_mfma_f32_16x16x32_f16(oa0, wov[(nt*2+0)*64+lane], acc,0,0,0);
      acc = __builtin_amdgcn_mfma_f32_16x16x32_f16(oa1, wov[(nt*2+1)*64+lane], acc,0,0,0);
      int col=nt*16+m; float bias=boL[col];
      #pragma unroll
      for(int rg=0;rg<4;rg++)
        y[nt][rg] = acc[rg] + bias + h2f(X[(w*16+q*4+rg)*72 + col]);
    }
    float mu[4], rs[4];
    #pragma unroll
    for(int rg=0;rg<4;rg++){
      float sm=(y[0][rg]+y[1][rg])+(y[2][rg]+y[3][rg]);
      sm+=__shfl_xor(sm,1); sm+=__shfl_xor(sm,2); sm+=__shfl_xor(sm,4); sm+=__shfl_xor(sm,8);
      mu[rg]=sm*(1.f/64.f);
      float d0=y[0][rg]-mu[rg],d1=y[1][rg]-mu[rg],d2=y[2][rg]-mu[rg],d3=y[3][rg]-mu[rg];
      float vv=(d0*d0+d1*d1)+(d2*d2+d3*d3);
      vv+=__shfl_xor(vv,1); vv+=__shfl_xor(vv,2); vv+=__shfl_xor(vv,4); vv+=__shfl_xor(vv,8);
      rs[rg]=rsqrtf(vv*(1.f/64.f)+1e-5f);
    }
    #pragma unroll
    for(int nt=0;nt<4;nt++){
      int col=nt*16+m; float g=g1L[col], be=be1L[col];
      #pragma unroll
      for(int rg=0;rg<4;rg++){
        float v=(y[nt][rg]-mu[rg])*rs[rg]*g+be;
        y[nt][rg]=v;                                  // FF residual (f32)
        QKV[(w*16+q*4+rg)*72 + col]=f2h(v);           // y -> wave-own rows
      }
    }

    // ---- FF1: y A-frags; H -> pitch-136 overlay ----
    half8 ya0 = *(const half8*)&QKV[r*72 + q*8];
    half8 ya1 = *(const half8*)&QKV[r*72 + 32 + q*8];
    #pragma unroll
    for(int nt=0;nt<8;nt++){
      f32x4 acc={0.f,0.f,0.f,0.f};
      acc = __builtin_amdgcn_mfma_f32_16x16x32_f16(ya0, w1v[(nt*2+0)*64+lane], acc,0,0,0);
      acc = __builtin_amdgcn_mfma_f32_16x16x32_f16(ya1, w1v[(nt*2+1)*64+lane], acc,0,0,0);
      float bias=b1L[nt*16+m];
      #pragma unroll
      for(int rg=0;rg<4;rg++)
        Hd[(w*16+q*4+rg)*136 + nt*16+m] = f2h(fmaxf(acc[rg]+bias, 0.f));
    }

    // ---- FF2 + residual y + LN2 ----
    half8 ha[4];
    #pragma unroll
    for(int c=0;c<4;c++)
      ha[c] = *(const half8*)&Hd[r*136 + c*32 + q*8];
    #pragma unroll
    for(int nt=0;nt<4;nt++){
      f32x4 acc={0.f,0.f,0.f,0.f};
      #pragma unroll
      for(int c=0;c<4;c++)
        acc = __builtin_amdgcn_mfma_f32_16x16x32_f16(ha[c], w2v[(nt*4+c)*64+lane], acc,0,0,0);
      int col=nt*16+m; float bias=b2L[col];
      #pragma unroll
      for(int rg=0;rg<4;rg++)
        y[nt][rg] = acc[rg] + bias + y[nt][rg];
    }
    #pragma unroll
    for(int rg=0;rg<4;rg++){
      float sm=(y[0][rg]+y[1][rg])+(y[2][rg]+y[3][rg]);
      sm+=__shfl_xor(sm,1); sm+=__shfl_xor(sm,2); sm+=__shfl_xor(sm,4); sm+=__shfl_xor(sm,8);
      mu[rg]=sm*(1.f/64.f);
      float d0=y[0][rg]-mu[rg],d1=y[1][rg]-mu[rg],d2=y[2][rg]-mu[rg],d3=y[3][rg]-mu[rg];
      float vv=(d0*d0+d1*d1)+(d2*d2+d3*d3);
      vv+=__shfl_xor(vv,1); vv+=__shfl_xor(vv,2); vv+=__shfl_xor(vv,4); vv+=__shfl_xor(vv,8);
      rs[rg]=rsqrtf(vv*(1.f/64.f)+1e-5f);
    }
    if(l==0){
      #pragma unroll
      for(int nt=0;nt<4;nt++){
        int col=nt*16+m; float g=g2L[col], be=be2L[col];
        #pragma unroll
        for(int rg=0;rg<4;rg++)
          X[(w*16+q*4+rg)*72 + col] = f2h((y[nt][rg]-mu[rg])*rs[rg]*g + be);
      }
      __syncthreads();   // before next layer's QKV scatter overwrites QKV regions
    } else {
      #pragma unroll
      for(int nt=0;nt<4;nt++){
        int col=nt*16+m; float g=g2L[col], be=be2L[col];
        #pragma unroll
        for(int rg=0;rg<4;rg++){
          if(trr[rg]==11)
            seq[base_rr[rg] + col] = f2h((y[nt][rg]-mu[rg])*rs[rg]*g + be);
        }
      }
    }
  }
}

// ---------------- prediction head (f16 seq in) ----------------
__global__ void k_head(const u16* __restrict__ seq, const float* __restrict__ Wh,
                       const float* __restrict__ bh, float* __restrict__ out){
  int m = blockIdx.x*256 + threadIdx.x; if(m>=M_) return;
  const u16* row = seq + ((size_t)11*M_ + m)*64;
  float a0=bh[0], a1=bh[1], a2=bh[2];
  #pragma unroll
  for(int d=0;d<64;d++){
    float x = h2f(row[d]);
    a0 += x*Wh[d]; a1 += x*Wh[64+d]; a2 += x*Wh[128+d];
  }
  unsigned b=(unsigned)m/N_, n=(unsigned)m-b*N_;
  out[(b*3+0)*N_+n] = a0;
  out[(b*3+1)*N_+n] = a1;
  out[(b*3+2)*N_+n] = a2;
}

extern "C" void kernel_launch(void* const* d_in, const int* in_sizes, int n_in,
                              void* d_out, int out_size, void* d_ws, size_t ws_size,
                              hipStream_t stream)
{
  const float* x_seq=(const float*)d_in[0];
  const int*   ei   =(const int*)d_in[1];
  const float* W1   =(const float*)d_in[2];
  const float* as1  =(const float*)d_in[3];
  const float* ad1  =(const float*)d_in[4];
  const float* b1   =(const float*)d_in[5];
  const float* W2   =(const float*)d_in[6];
  const float* as2  =(const float*)d_in[7];
  const float* ad2  =(const float*)d_in[8];
  const float* b2   =(const float*)d_in[9];
  const float* Wqkv =(const float*)d_in[10];
  const float* bqkv =(const float*)d_in[11];
  const float* Wo   =(const float*)d_in[12];
  const float* bo   =(const float*)d_in[13];
  const float* Wf1  =(const float*)d_in[14];
  const float* bf1p =(const float*)d_in[15];
  const float* Wf2  =(const float*)d_in[16];
  const float* bf2p =(const float*)d_in[17];
  const float* g1   =(const float*)d_in[18];
  const float* be1  =(const float*)d_in[19];
  const float* g2   =(const float*)d_in[20];
  const float* be2  =(const float*)d_in[21];
  const float* Wh   =(const float*)d_in[22];
  const float* bh   =(const float*)d_in[23];

  // workspace layout (~112 MB)
  u16* seqh   = (u16*)d_ws;                     // [T][M][64] f16  24,576,000 u16
  float* asc  = (float*)(seqh + 24576000);      // [T][M][4]        1,536,000 f
  float* adc  = asc + 1536000;                  //                  1,536,000 f
  int* deg    = (int*)(adc + 1536000);
  int* cursor = deg + M_;
  int* offs   = cursor + M_;                    // M_+1 used
  int* bsums  = offs + (M_ + 2);
  int* boffs  = bsums + 128;
  int* csr    = boffs + 128;                    // ETOT
  u16* h2u    = (u16*)(csr + ETOT);             // [T][M][64]   24,576,000 u16
  u16* wqB    = h2u + (size_t)T_*M_*64;         // 24576
  u16* woB    = wqB + 24576;                    // 8192
  u16* w1B    = woB + 8192;                     // 16384
  u16* w2B    = w1B + 16384;                    // 16384
  float* peT  = (float*)(w2B + 16384);          // 768

  k_prep   <<<dim3(260), dim3(256), 0, stream>>>(Wqkv, Wo, Wf1, Wf2, wqB, woB, w1B, w2B, peT);

  // CSR build (edge list identical for all t)
  hipMemsetAsync(deg, 0, (size_t)2*M_*sizeof(int), stream);   // deg + cursor
  k_hist   <<<dim3((ETOT+255)/256), dim3(256), 0, stream>>>(ei, deg);
  k_scan1  <<<dim3(125), dim3(256), 0, stream>>>(deg, offs, bsums);
  k_scan2  <<<dim3(1),   dim3(128), 0, stream>>>(bsums, boffs);
  k_scan3  <<<dim3(125), dim3(256), 0, stream>>>(offs, boffs);
  k_scatter<<<dim3((ETOT+255)/256), dim3(256), 0, stream>>>(ei, offs, cursor, csr);

  k_gat12<<<dim3(500,T_), dim3(256), 0, stream>>>(x_seq, W1, as1, ad1, b1,
                                                  W2, as2, ad2, offs, csr, h2u, asc, adc);
  k_gat2b<<<dim3(500,T_), dim3(256), 0, stream>>>(h2u, asc, adc, b2, offs, csr, peT, seqh);

  k_layer2<<<dim3(8000), dim3(192), 0, stream>>>(seqh,
      wqB, woB, w1B, w2B,
      bqkv, bo, bf1p, bf2p,
      g1, be1, g2, be2);

  k_head<<<dim3(125), dim3(256), 0, stream>>>(seqh, Wh, bh, (float*)d_out);
}